// Round 1
// baseline (266.809 us; speedup 1.0000x reference)
//
#include <hip/hip_runtime.h>
#include <hip/hip_bf16.h>

// LSTM B=8192,T=512,I=3,H=25 + linear[H->1], bf16 MFMA 16x16x32.
// R13: TWO independent 16-batch chains per block (32 batches, 256 blocks,
// 1 block/CU, 7 waves/CU). Rationale (R11/R12 counters): period(2 tile-steps)
// = 954cy = 534 issue + 420 EXPOSED chain, because all resident waves
// phase-lock at the same barrier. Fusing 2 chains into one block:
//  - each wave issues tileA + tileB back-to-back -> B's issue fills A's
//    ds_read->MFMA->exp chain by construction (no scheduler luck needed)
//  - ONE __syncthreads now retires TWO tile-steps (barrier count halved)
//  - activation glue packed v_pk_*_f32 across the (A,B) pair; trans
//    (5 exp2 + 3 rcp per unit) stay scalar x2 (1/4-rate floor)
//  - x-feed duty moved to wave 3 (lone wave on its SIMD) for issue balance
// Kept from R12: unmasked pad-slot h-writes (u=25..27 -> slots 29..31, A=0),
// bare ds_read_b128 -> MFMA, register-resident A-frag, hoisted restage
// (CHUNK=128 now, 4 chunks, same boundary pattern).

#define TSTEPS 512
#define ISZ 3
#define HSZ 25
#define NW 7
#define CHUNK 128
#define TSTRIDE 40          // shorts per batch row (80 B)

typedef __attribute__((ext_vector_type(8))) short bf16x8;
typedef __attribute__((ext_vector_type(4))) float f32x4;
typedef __attribute__((ext_vector_type(2))) float v2f;

__device__ __forceinline__ unsigned short bf16_bits(float v) {
    return __builtin_bit_cast(unsigned short, __float2bfloat16(v));
}
__device__ __forceinline__ unsigned int pack_bf16(float lo, float hi) {
    return ((unsigned int)bf16_bits(hi) << 16) | (unsigned int)bf16_bits(lo);
}
__device__ __forceinline__ v2f rcp2(v2f v) {
    return (v2f){__builtin_amdgcn_rcpf(v.x), __builtin_amdgcn_rcpf(v.y)};
}

__global__ __launch_bounds__(NW * 64) void lstm_mfma(
    const float* __restrict__ x,      // [B, T, I]
    const float* __restrict__ w_ih,   // [4H, I]
    const float* __restrict__ w_hh,   // [4H, H]
    const float* __restrict__ b_ih,   // [4H]
    const float* __restrict__ b_hh,   // [4H]
    const float* __restrict__ w_lin,  // [1, H]
    const float* __restrict__ b_lin,  // [1]
    float* __restrict__ out)          // [B, 1]
{
    __shared__ uint2 xpkA[CHUNK][16];         // 16 KB packed bf16 x (+1.0), tile A
    __shared__ uint2 xpkB[CHUNK][16];         // 16 KB, tile B
    __shared__ short hbA[2][16 * TSTRIDE];    // parity-buffered B-rows, tile A
    __shared__ short hbB[2][16 * TSTRIDE];    // tile B
    __shared__ float outred[NW][32];

    const int tid  = threadIdx.x;
    const int w    = tid >> 6;       // wave 0..6: frag tile T=w (units 4w..4w+3)
    const int lane = tid & 63;
    const int n    = lane & 15;      // batch within tile
    const int q    = lane >> 4;      // quad -> unit u = 4w + q
    const int u    = 4 * w + q;
    // x-feed lanes: wave 3 (alone on its SIMD), q==1 -> tile A, q==2 -> tile B
    const bool isxf = (w == 3) && ((unsigned)(q - 1) < 2u);

    // zero both parity buffers of both tiles (h(0)=0)
    for (int i = tid; i < 2 * 16 * TSTRIDE; i += NW * 64) {
        ((short*)hbA)[i] = 0;
        ((short*)hbB)[i] = 0;
    }

    // ---- stage one 128-step chunk of x (pre-packed bf16), 256 threads ----
    auto stagepass = [&](int c0, int rowbase, uint2 (*dst)[16]) {
        if (tid < 256) {
            const int bsel = tid >> 4, sub16 = tid & 15;
            const float* __restrict__ g =
                x + (size_t)(rowbase + bsel) * (TSTEPS * ISZ) + c0 * ISZ;
            #pragma unroll
            for (int it = 0; it < CHUNK / 64; ++it) {
                const int tg = sub16 + 16 * it;        // 4-step groups 0..31
                const float4* f4 = (const float4*)(g + tg * 12);
                float4 a = f4[0], b4 = f4[1], c4 = f4[2];
                const float s[4][3] = { {a.x, a.y, a.z}, {a.w, b4.x, b4.y},
                                        {b4.z, b4.w, c4.x}, {c4.y, c4.z, c4.w} };
                #pragma unroll
                for (int uu = 0; uu < 4; ++uu) {
                    uint2 d;
                    d.x = pack_bf16(s[uu][0], s[uu][1]);
                    d.y = pack_bf16(s[uu][2], 1.0f);
                    dst[tg * 4 + uu][bsel] = d;
                }
            }
        }
    };
    auto stage = [&](int c0) {
        stagepass(c0, blockIdx.x * 32, xpkA);
        stagepass(c0, blockIdx.x * 32 + 16, xpkB);
    };
    stage(0);

    // ---- this wave's A fragment (loaded once, register-resident, SHARED by
    //      both tiles' MFMAs) ----
    // A[r=16w+n][k=q*8+j]; row r=4u'+g (unit-major); k: [w_ih 0..2, bias 3, w_hh 4..28]
    bf16x8 afrag;
    #pragma unroll
    for (int j = 0; j < 8; ++j) {
        const int k = q * 8 + j;
        const int r = 16 * w + n;
        const int uu = r >> 2, g = r & 3;
        float v = 0.0f;
        if (uu < HSZ) {
            const int orow = g * HSZ + uu;             // original i,f,g,o order
            if (k < ISZ)            v = w_ih[orow * ISZ + k];
            else if (k == ISZ)      v = b_ih[orow] + b_hh[orow];
            else if (k < 4 + HSZ)   v = w_hh[orow * HSZ + (k - 4)];
        }
        afrag[j] = (short)bf16_bits(v);
    }

    __syncthreads();

    // x(slot) -> hb[wp] slots 0..3 (wave-3 lanes q=1/2 handle tiles A/B)
    auto xfeed = [&](int slot, int wp) {
        if (isxf) {
            const uint2* src = (q == 1) ? &xpkA[slot][n] : &xpkB[slot][n];
            short*       dst = (q == 1) ? hbA[wp] : hbB[wp];
            *(uint2*)&dst[n * TSTRIDE] = *src;
        }
    };
    xfeed(0, 0);     // seed x(0) into parity-0 rows
    __syncthreads();

    v2f c = {0.f, 0.f}, h = {0.f, 0.f};      // packed (tileA, tileB) state
    const int rdoff = n * TSTRIDE + q * 8;
    const int wroff = n * TSTRIDE + 4 + u;    // u up to 27 -> slot <= 31 (pad, A=0)
    const float K1 = 1.442695040888963f;      // log2 e
    const float K2 = 2.885390081777927f;      // 2 log2 e

    auto step = [&](int t, int rp, int wp) {
        // bare ds_read_b128 -> MFMA, both tiles back-to-back (independent)
        const bf16x8 bA = *reinterpret_cast<const bf16x8*>(&hbA[rp][rdoff]);
        const bf16x8 bB = *reinterpret_cast<const bf16x8*>(&hbB[rp][rdoff]);
        const f32x4 aA = __builtin_amdgcn_mfma_f32_16x16x32_bf16(
            afrag, bA, (f32x4){0.f, 0.f, 0.f, 0.f}, 0, 0, 0);
        const f32x4 aB = __builtin_amdgcn_mfma_f32_16x16x32_bf16(
            afrag, bB, (f32x4){0.f, 0.f, 0.f, 0.f}, 0, 0, 0);

        // acts: same math as R12 per tile; glue packed v_pk across (A,B)
        const v2f e0 = {__builtin_amdgcn_exp2f(-K1 * aA[0]),
                        __builtin_amdgcn_exp2f(-K1 * aB[0])};
        const v2f e1 = {__builtin_amdgcn_exp2f(-K1 * aA[1]),
                        __builtin_amdgcn_exp2f(-K1 * aB[1])};
        const v2f e2 = {__builtin_amdgcn_exp2f(fminf(-K2 * aA[2], 126.0f)),
                        __builtin_amdgcn_exp2f(fminf(-K2 * aB[2], 126.0f))};
        const v2f e3 = {__builtin_amdgcn_exp2f(-K1 * aA[3]),
                        __builtin_amdgcn_exp2f(-K1 * aB[3])};
        const v2f ff = rcp2(e1 + 1.0f);
        const v2f ig = (1.0f - e2) * rcp2((e0 + 1.0f) * (e2 + 1.0f));
        c = ff * c + ig;                                   // v_pk_fma_f32
        const v2f ec = {__builtin_amdgcn_exp2f(fminf(-K2 * c.x, 126.0f)),
                        __builtin_amdgcn_exp2f(fminf(-K2 * c.y, 126.0f))};
        h = (1.0f - ec) * rcp2((e3 + 1.0f) * (1.0f + ec));

        hbA[wp][wroff] = (short)bf16_bits(h.x);   // unmasked (pad-slot trick)
        hbB[wp][wroff] = (short)bf16_bits(h.y);
        xfeed((t + 1) & (CHUNK - 1), wp);
        __syncthreads();                          // ONE barrier per 2 tile-steps
    };

    // ---- 4 chunks x 128 steps; restage hoisted to chunk boundary ----
    #pragma unroll 1
    for (int ch = 0; ch < 4; ++ch) {
        const int t0 = ch * CHUNK;
        #pragma unroll 1
        for (int p = 0; p < 63; ++p) {
            step(t0 + 2 * p, 0, 1);
            step(t0 + 2 * p + 1, 1, 0);
        }
        // boundary: step t0+126 reads x(t0+127) (old chunk); restage;
        // step t0+127 reads x(t0+128) (new chunk)
        step(t0 + 126, 0, 1);
        if (ch < 3) stage((ch + 1) * CHUNK);
        __syncthreads();
        step(t0 + 127, 1, 0);
    }

    // ---- final linear: out[b] = sum_u w_lin[u]*h[u] + b_lin, both tiles ----
    const float wl = (u < HSZ) ? w_lin[u] : 0.0f;
    v2f v = h * wl;
    v.x += __shfl_xor(v.x, 16);
    v.y += __shfl_xor(v.y, 16);
    v.x += __shfl_xor(v.x, 32);
    v.y += __shfl_xor(v.y, 32);
    if (lane < 16) {
        outred[w][lane]      = v.x;     // tile A -> batches 0..15
        outred[w][16 + lane] = v.y;     // tile B -> batches 16..31
    }
    __syncthreads();
    if (tid < 32) {
        float s = b_lin[0];
        #pragma unroll
        for (int k = 0; k < NW; ++k) s += outred[k][tid];
        out[blockIdx.x * 32 + tid] = s;
    }
}

extern "C" void kernel_launch(void* const* d_in, const int* in_sizes, int n_in,
                              void* d_out, int out_size, void* d_ws, size_t ws_size,
                              hipStream_t stream) {
    const float* x     = (const float*)d_in[0];
    const float* w_ih  = (const float*)d_in[1];
    const float* w_hh  = (const float*)d_in[2];
    const float* b_ih  = (const float*)d_in[3];
    const float* b_hh  = (const float*)d_in[4];
    const float* w_lin = (const float*)d_in[5];
    const float* b_lin = (const float*)d_in[6];
    float* out = (float*)d_out;

    lstm_mfma<<<8192 / 32, NW * 64, 0, stream>>>(x, w_ih, w_hh, b_ih, b_hh,
                                                 w_lin, b_lin, out);
}